// Round 11
// baseline (375.268 us; speedup 1.0000x reference)
//
#include <hip/hip_runtime.h>

typedef unsigned int uint;
typedef float f32x2 __attribute__((ext_vector_type(2)));

#define N_NODES 100000
#define N_EDGES 3200000
#define IN_CH 128
#define HID 64
#define N_GRAPHS 512
#define EPB 4096                                   // edges per block (binning)
#define NBLK ((N_EDGES + EPB - 1) / EPB)           // 782
#define NB 391                                     // buckets = dst>>8 (256 nodes each)
#define CAP 10240                                  // bucket capacity (mean 8192, 22 sigma)

// ---------------------------------------------------------------------------
// bf16 helpers: A and B matrices are packed bf16 (uint = 2 channels)
__device__ __forceinline__ uint f2bf1(float f) {
    union { float f; uint i; } v; v.f = f;
    return (v.i + 0x7fffu + ((v.i >> 16) & 1u)) >> 16;    // RNE
}
__device__ __forceinline__ uint pack2(float lo, float hi) {
    return f2bf1(lo) | (f2bf1(hi) << 16);
}
__device__ __forceinline__ float2 ub2(uint u) {
    union { uint i; float f; } a, b;
    a.i = u << 16; b.i = u & 0xffff0000u;
    return make_float2(a.f, b.f);
}
// unpack to ext-vector float2 (v_pk_add_f32-friendly accumulation)
__device__ __forceinline__ f32x2 up2(uint u) {
    union { uint i; float f; } lo, hi;
    lo.i = u << 16; hi.i = u & 0xffff0000u;
    f32x2 r; r.x = lo.f; r.y = hi.f;
    return r;
}

// ---------------------------------------------------------------------------
// Two-pass multisplit (no register edge-cache -> no spill):
// pass 1: read dst, LDS bucket histogram (4 wave-replicated copies);
// reserve per-(bucket,block) ranges with one padded global atomic;
// pass 2: re-read src+dst (L2-hot), scatter packed pairs via LDS cursors.
__global__ __launch_bounds__(256) void scatter_kernel(const int* __restrict__ src,
                                                      const int* __restrict__ dst,
                                                      int* __restrict__ bcnt,
                                                      uint* __restrict__ pairs) {
    __shared__ int h[4 * NB];
    __shared__ int start[NB];
    __shared__ int cur[NB];
    int t = threadIdx.x;
    int base = blockIdx.x * EPB;
    int end = min(base + EPB, N_EDGES);

    for (int i = t; i < 4 * NB; i += 256) h[i] = 0;
    __syncthreads();
    int w = t >> 6;
    for (int e = base + t; e < end; e += 256)
        atomicAdd(&h[w * NB + (dst[e] >> 8)], 1);
    __syncthreads();
    for (int b = t; b < NB; b += 256) {
        int tot = h[b] + h[NB + b] + h[2 * NB + b] + h[3 * NB + b];
        start[b] = tot ? atomicAdd(&bcnt[b * 16], tot) : 0;
        cur[b] = 0;
    }
    __syncthreads();
    for (int e = base + t; e < end; e += 256) {
        int d = dst[e];                 // L2-hot re-read
        int s = src[e];
        int b = d >> 8;
        int r = atomicAdd(&cur[b], 1);
        pairs[(size_t)b * CAP + start[b] + r] =
            ((uint)(d & 255) << 24) | (uint)s;   // src < 2^17
    }
}

// ---------------------------------------------------------------------------
// Per-bucket CSR build (256-node buckets, 512 threads): LDS histogram -> scan
// -> rstart/rend/dis (plain stores) -> LDS-cursor fill of csr_src.
__global__ __launch_bounds__(512) void bucket_csr_kernel(const uint* __restrict__ pairs,
                                                         const int* __restrict__ bcnt,
                                                         int* __restrict__ csr_src,
                                                         int* __restrict__ rstart,
                                                         int* __restrict__ rend,
                                                         float* __restrict__ dis) {
    __shared__ int h[256];
    int b = blockIdx.x;
    int t = threadIdx.x;
    int e0 = b * CAP;
    int e1 = e0 + bcnt[b * 16];
    if (t < 256) h[t] = 0;
    __syncthreads();
    for (int e = e0 + t; e < e1; e += 512)
        atomicAdd(&h[pairs[e] >> 24], 1);
    __syncthreads();
    int v = (t < 256) ? h[t] : 0;       // in-degree of node b*256+t
#pragma unroll
    for (int o = 1; o < 256; o <<= 1) {
        int x = (t >= o && t < 256) ? h[t - o] : 0;
        __syncthreads();
        if (t < 256) h[t] += x;
        __syncthreads();
    }
    int excl = (t < 256) ? h[t] - v : 0;
    int n = b * 256 + t;
    if (t < 256 && n < N_NODES) {
        rstart[n] = e0 + excl;
        rend[n] = e0 + excl + v;
        dis[n] = rsqrtf((float)v + 1.0f);
    }
    __syncthreads();
    if (t < 256) h[t] = e0 + excl;      // cursor
    __syncthreads();
    for (int e = e0 + t; e < e1; e += 512) {
        uint p = pairs[e];
        int pos = atomicAdd(&h[p >> 24], 1);
        csr_src[pos] = (int)(p & 0xFFFFFFu);
    }
}

// ---------------------------------------------------------------------------
// GEMM1: Y[M,64](bf16) = (X[M,128] @ W[128,64]) * dis[row].  X fp32.
// block: 128 rows x 64 ch; thread: 4 rows x 8 ch. Register-prefetch staging.
__global__ __launch_bounds__(256) void gemm1_kernel(const float* __restrict__ X,
                                                    const float* __restrict__ W,
                                                    const float* __restrict__ dis,
                                                    uint* __restrict__ Y) {
    __shared__ float Wl[IN_CH * 64];
    __shared__ float Xs[128 * 33];
    int t = threadIdx.x;
    for (int idx = t; idx < IN_CH * 64; idx += 256) Wl[idx] = W[idx];

    int r0 = (t >> 3) * 4;
    int c0 = (t & 7) * 8;
    int rowBase = blockIdx.x * 128;

    float acc[4][8];
#pragma unroll
    for (int a = 0; a < 4; ++a)
#pragma unroll
        for (int c = 0; c < 8; ++c) acc[a][c] = 0.f;

    int srow = t >> 1;
    int shh = (t & 1) * 16;
    bool sok = (rowBase + srow) < N_NODES;
    const float* xbase = X + (size_t)(rowBase + srow) * IN_CH + shh;

    float4 nx[4];
#pragma unroll
    for (int f = 0; f < 4; ++f)
        nx[f] = sok ? *reinterpret_cast<const float4*>(xbase + f * 4)
                    : make_float4(0.f, 0.f, 0.f, 0.f);

    for (int kc = 0; kc < IN_CH; kc += 32) {
        if (kc) __syncthreads();
#pragma unroll
        for (int f = 0; f < 4; ++f) {
            int o = srow * 33 + shh + f * 4;
            Xs[o] = nx[f].x; Xs[o + 1] = nx[f].y; Xs[o + 2] = nx[f].z; Xs[o + 3] = nx[f].w;
        }
        __syncthreads();
        if (kc + 32 < IN_CH) {
#pragma unroll
            for (int f = 0; f < 4; ++f)
                nx[f] = sok ? *reinterpret_cast<const float4*>(xbase + kc + 32 + f * 4)
                            : make_float4(0.f, 0.f, 0.f, 0.f);
        }
#pragma unroll
        for (int kk = 0; kk < 32; ++kk) {
            const float4 wa = *reinterpret_cast<const float4*>(&Wl[(kc + kk) * 64 + c0]);
            const float4 wb = *reinterpret_cast<const float4*>(&Wl[(kc + kk) * 64 + c0 + 4]);
            float xr[4];
#pragma unroll
            for (int a = 0; a < 4; ++a) xr[a] = Xs[(r0 + a) * 33 + kk];
#pragma unroll
            for (int a = 0; a < 4; ++a) {
                acc[a][0] += xr[a] * wa.x; acc[a][1] += xr[a] * wa.y;
                acc[a][2] += xr[a] * wa.z; acc[a][3] += xr[a] * wa.w;
                acc[a][4] += xr[a] * wb.x; acc[a][5] += xr[a] * wb.y;
                acc[a][6] += xr[a] * wb.z; acc[a][7] += xr[a] * wb.w;
            }
        }
    }
#pragma unroll
    for (int a = 0; a < 4; ++a) {
        int row = rowBase + r0 + a;
        if (row < N_NODES) {
            float d = dis[row];
            uint4 o;
            o.x = pack2(acc[a][0] * d, acc[a][1] * d);
            o.y = pack2(acc[a][2] * d, acc[a][3] * d);
            o.z = pack2(acc[a][4] * d, acc[a][5] * d);
            o.w = pack2(acc[a][6] * d, acc[a][7] * d);
            *reinterpret_cast<uint4*>(Y + (size_t)row * 32 + (t & 7) * 4) = o;
        }
    }
}

// ---------------------------------------------------------------------------
// GEMM2: Y[M,64](bf16) = (relu(X)[M,64] @ W[64,64]) * dis[row].  X bf16 packed.
__global__ __launch_bounds__(256) void gemm2_kernel(const uint* __restrict__ X,
                                                    const float* __restrict__ W,
                                                    const float* __restrict__ dis,
                                                    uint* __restrict__ Y) {
    __shared__ float Wl[HID * 64];
    __shared__ float Xs[128 * 33];
    int t = threadIdx.x;
    for (int idx = t; idx < HID * 64; idx += 256) Wl[idx] = W[idx];

    int r0 = (t >> 3) * 4;
    int c0 = (t & 7) * 8;
    int rowBase = blockIdx.x * 128;

    float acc[4][8];
#pragma unroll
    for (int a = 0; a < 4; ++a)
#pragma unroll
        for (int c = 0; c < 8; ++c) acc[a][c] = 0.f;

    int srow = t >> 1;
    int shh = (t & 1) * 16;
    bool sok = (rowBase + srow) < N_NODES;
    const uint* xbase = X + (size_t)(rowBase + srow) * 32 + (t & 1) * 8;

    uint4 n0_ = make_uint4(0, 0, 0, 0), n1_ = n0_;
    if (sok) {
        n0_ = *reinterpret_cast<const uint4*>(xbase);
        n1_ = *reinterpret_cast<const uint4*>(xbase + 4);
    }

    for (int kc = 0; kc < HID; kc += 32) {
        if (kc) __syncthreads();
        {
            uint us[8] = {n0_.x, n0_.y, n0_.z, n0_.w, n1_.x, n1_.y, n1_.z, n1_.w};
            int o = srow * 33 + shh;
#pragma unroll
            for (int j = 0; j < 8; ++j) {
                float2 f = ub2(us[j]);
                Xs[o + 2 * j]     = fmaxf(f.x, 0.f);
                Xs[o + 2 * j + 1] = fmaxf(f.y, 0.f);
            }
        }
        __syncthreads();
        if (kc + 32 < HID && sok) {
            n0_ = *reinterpret_cast<const uint4*>(xbase + 16);
            n1_ = *reinterpret_cast<const uint4*>(xbase + 20);
        }
#pragma unroll
        for (int kk = 0; kk < 32; ++kk) {
            const float4 wa = *reinterpret_cast<const float4*>(&Wl[(kc + kk) * 64 + c0]);
            const float4 wb = *reinterpret_cast<const float4*>(&Wl[(kc + kk) * 64 + c0 + 4]);
            float xr[4];
#pragma unroll
            for (int a = 0; a < 4; ++a) xr[a] = Xs[(r0 + a) * 33 + kk];
#pragma unroll
            for (int a = 0; a < 4; ++a) {
                acc[a][0] += xr[a] * wa.x; acc[a][1] += xr[a] * wa.y;
                acc[a][2] += xr[a] * wa.z; acc[a][3] += xr[a] * wa.w;
                acc[a][4] += xr[a] * wb.x; acc[a][5] += xr[a] * wb.y;
                acc[a][6] += xr[a] * wb.z; acc[a][7] += xr[a] * wb.w;
            }
        }
    }
#pragma unroll
    for (int a = 0; a < 4; ++a) {
        int row = rowBase + r0 + a;
        if (row < N_NODES) {
            float d = dis[row];
            uint4 o;
            o.x = pack2(acc[a][0] * d, acc[a][1] * d);
            o.y = pack2(acc[a][2] * d, acc[a][3] * d);
            o.z = pack2(acc[a][4] * d, acc[a][5] * d);
            o.w = pack2(acc[a][6] * d, acc[a][7] * d);
            *reinterpret_cast<uint4*>(Y + (size_t)row * 32 + (t & 7) * 4) = o;
        }
    }
}

// ---------------------------------------------------------------------------
// wave per node, 8 edges concurrent (8 lanes/edge, bf16x8 = 16B per lane),
// 16-edge unroll, f32x2 packed accumulation (v_pk_add_f32):
// B[i] = bf16(bias + dis[i] * (A'[i] + sum A'[src])),  A' = (X@W)*dis  (bf16)
__global__ __launch_bounds__(256) void gather_kernel(const int* __restrict__ rstart,
                                                     const int* __restrict__ rend,
                                                     const int* __restrict__ csr_src,
                                                     const float* __restrict__ dis,
                                                     const float* __restrict__ bias,
                                                     const uint* __restrict__ A,
                                                     uint* __restrict__ B) {
    int i = blockIdx.x * 4 + (threadIdx.x >> 6);
    if (i >= N_NODES) return;
    int lane = threadIdx.x & 63;
    int q = lane >> 3;               // which of 8 concurrent edges
    int cu = (lane & 7) * 4;         // uint4 offset in 32-uint row (8 channels)

    float4 bi0 = *reinterpret_cast<const float4*>(&bias[(lane & 7) * 8]);
    float4 bi1 = *reinterpret_cast<const float4*>(&bias[(lane & 7) * 8 + 4]);

    int e = rstart[i];
    int end = rend[i];

    f32x2 a[4], b[4];
#pragma unroll
    for (int j = 0; j < 4; ++j) { a[j] = (f32x2)0.f; b[j] = (f32x2)0.f; }

    if (q == 0) {                    // self term (already *dis[i])
        uint4 u = *reinterpret_cast<const uint4*>(&A[(size_t)i * 32 + cu]);
        a[0] += up2(u.x); a[1] += up2(u.y); a[2] += up2(u.z); a[3] += up2(u.w);
    }
    for (; e + 16 <= end; e += 16) {
        int s0 = csr_src[e + q];
        int s1 = csr_src[e + 8 + q];
        uint4 u0 = *reinterpret_cast<const uint4*>(&A[(size_t)s0 * 32 + cu]);
        uint4 u1 = *reinterpret_cast<const uint4*>(&A[(size_t)s1 * 32 + cu]);
        a[0] += up2(u0.x); a[1] += up2(u0.y); a[2] += up2(u0.z); a[3] += up2(u0.w);
        b[0] += up2(u1.x); b[1] += up2(u1.y); b[2] += up2(u1.z); b[3] += up2(u1.w);
    }
    for (; e + 8 <= end; e += 8) {
        int s = csr_src[e + q];
        uint4 u = *reinterpret_cast<const uint4*>(&A[(size_t)s * 32 + cu]);
        a[0] += up2(u.x); a[1] += up2(u.y); a[2] += up2(u.z); a[3] += up2(u.w);
    }
    if (e + q < end) {
        int s = csr_src[e + q];
        uint4 u = *reinterpret_cast<const uint4*>(&A[(size_t)s * 32 + cu]);
        b[0] += up2(u.x); b[1] += up2(u.y); b[2] += up2(u.z); b[3] += up2(u.w);
    }
    float r[8];
#pragma unroll
    for (int j = 0; j < 4; ++j) {
        f32x2 s = a[j] + b[j];
        r[2 * j] = s.x; r[2 * j + 1] = s.y;
    }
#pragma unroll
    for (int j = 0; j < 8; ++j) {
        r[j] += __shfl_xor(r[j], 8);
        r[j] += __shfl_xor(r[j], 16);
        r[j] += __shfl_xor(r[j], 32);
    }
    if (q == 0) {
        float d = dis[i];
        uint4 o;
        o.x = pack2(bi0.x + d * r[0], bi0.y + d * r[1]);
        o.y = pack2(bi0.z + d * r[2], bi0.w + d * r[3]);
        o.z = pack2(bi1.x + d * r[4], bi1.y + d * r[5]);
        o.w = pack2(bi1.z + d * r[6], bi1.w + d * r[7]);
        *reinterpret_cast<uint4*>(B + (size_t)i * 32 + (lane & 7) * 4) = o;
    }
}

// ---------------------------------------------------------------------------
// pool over bf16 B: batch is sorted -> run-length accumulate per half-wave
// (16 nodes each; 32 lanes x 2 ch cover the 64-ch row), relu fused.
__global__ __launch_bounds__(256) void pool_kernel(const uint* __restrict__ B,
                                                   const int* __restrict__ batch,
                                                   float* __restrict__ sums,
                                                   float* __restrict__ cnt) {
    int w = blockIdx.x * 4 + (threadIdx.x >> 6);
    int half = (threadIdx.x >> 5) & 1;
    int l = threadIdx.x & 31;           // uint index (channels 2l, 2l+1)
    int n0 = w * 32 + half * 16;
    if (n0 >= N_NODES) return;
    int n1 = min(n0 + 16, N_NODES);
    int curg = batch[n0];
    float a0 = 0.f, a1 = 0.f;
    int run = 0;
    for (int n = n0; n < n1; ++n) {
        int g = batch[n];
        if (g != curg) {
            atomicAdd(&sums[curg * 64 + 2 * l], a0);
            atomicAdd(&sums[curg * 64 + 2 * l + 1], a1);
            if (l == 0) atomicAdd(&cnt[curg], (float)run);
            curg = g; a0 = 0.f; a1 = 0.f; run = 0;
        }
        float2 f = ub2(B[(size_t)n * 32 + l]);
        a0 += fmaxf(f.x, 0.f);
        a1 += fmaxf(f.y, 0.f);
        run++;
    }
    atomicAdd(&sums[curg * 64 + 2 * l], a0);
    atomicAdd(&sums[curg * 64 + 2 * l + 1], a1);
    if (l == 0) atomicAdd(&cnt[curg], (float)run);
}

__global__ __launch_bounds__(256) void final_kernel(const float* __restrict__ sums,
                                                    const float* __restrict__ cnt,
                                                    float* __restrict__ out) {
    int idx = blockIdx.x * 256 + threadIdx.x;
    if (idx < N_GRAPHS * 64) out[idx] = sums[idx] / fmaxf(cnt[idx >> 6], 1.0f);
}

// ---------------------------------------------------------------------------
extern "C" void kernel_launch(void* const* d_in, const int* in_sizes, int n_in,
                              void* d_out, int out_size, void* d_ws, size_t ws_size,
                              hipStream_t stream) {
    const float* x     = (const float*)d_in[0];
    const int*   edge  = (const int*)d_in[1];   // [2, E]: row0 = src, row1 = dst
    const int*   batch = (const int*)d_in[2];
    const float* W1    = (const float*)d_in[3];
    const float* b1    = (const float*)d_in[4];
    const float* W2    = (const float*)d_in[5];
    const float* b2    = (const float*)d_in[6];
    float* out = (float*)d_out;

    // workspace layout (elements)
    uint*  A        = (uint*)d_ws;                        // 3,200,000 u (bf16 A)
    uint*  B        = A + (size_t)N_NODES * 32;           // 3,200,000 u (bf16 B)
    uint*  pairs    = B + (size_t)N_NODES * 32;           // NB*CAP = 4,003,840 u
    int*   csr_src  = (int*)(pairs + (size_t)NB * CAP);   // NB*CAP = 4,003,840 i
    float* dis      = (float*)(csr_src + (size_t)NB * CAP); // 100,000 f
    int*   rstart   = (int*)(dis + N_NODES);              // 100,000 i
    int*   rend     = rstart + N_NODES;                   // 100,000 i
    float* sums     = (float*)(rend + N_NODES);           // 32,768 f
    float* cnt_f    = sums + (size_t)N_GRAPHS * 64;       // 512 f
    int*   bcnt     = (int*)(cnt_f + N_GRAPHS);           // NB*16 = 6,256 i (padded)
    // total ~59 MB

    const int* src = edge;
    const int* dst = edge + N_EDGES;

    // zero sums + cnt + bcnt in one shot (contiguous)
    hipMemsetAsync(sums, 0, (N_GRAPHS * 64 + N_GRAPHS + NB * 16) * sizeof(float), stream);

    // CSR build: two-pass multisplit + per-bucket local fill
    scatter_kernel<<<NBLK, 256, 0, stream>>>(src, dst, bcnt, pairs);
    bucket_csr_kernel<<<NB, 512, 0, stream>>>(pairs, bcnt, csr_src, rstart, rend, dis);

    // layer 1: A = bf16((x@W1)*dis) ; B = bf16(b1 + dis*(A[i] + sum A[src]))
    gemm1_kernel<<<(N_NODES + 127) / 128, 256, 0, stream>>>(x, W1, dis, A);
    gather_kernel<<<(N_NODES + 3) / 4, 256, 0, stream>>>(rstart, rend, csr_src, dis, b1, A, B);

    // layer 2 (relu fused into GEMM2 staging)
    gemm2_kernel<<<(N_NODES + 127) / 128, 256, 0, stream>>>(B, W2, dis, A);
    gather_kernel<<<(N_NODES + 3) / 4, 256, 0, stream>>>(rstart, rend, csr_src, dis, b2, A, B);

    // pool (relu fused) + finalize
    pool_kernel<<<(N_NODES + 127) / 128, 256, 0, stream>>>(B, batch, sums, cnt_f);
    final_kernel<<<(N_GRAPHS * 64 + 255) / 256, 256, 0, stream>>>(sums, cnt_f, out);
}

// Round 12
// 358.682 us; speedup vs baseline: 1.0462x; 1.0462x over previous
//
#include <hip/hip_runtime.h>

typedef unsigned int uint;
typedef float f32x2 __attribute__((ext_vector_type(2)));

#define N_NODES 100000
#define N_EDGES 3200000
#define IN_CH 128
#define HID 64
#define N_GRAPHS 512
#define EPB 4096                                   // edges per block (binning)
#define NBLK ((N_EDGES + EPB - 1) / EPB)           // 782
#define NB 391                                     // buckets = dst>>8 (256 nodes each)
#define CAP 10240                                  // bucket capacity (mean 8192, 22 sigma)

// ---------------------------------------------------------------------------
// bf16 helpers: A and B matrices are packed bf16 (uint = 2 channels)
__device__ __forceinline__ uint f2bf1(float f) {
    union { float f; uint i; } v; v.f = f;
    return (v.i + 0x7fffu + ((v.i >> 16) & 1u)) >> 16;    // RNE
}
__device__ __forceinline__ uint pack2(float lo, float hi) {
    return f2bf1(lo) | (f2bf1(hi) << 16);
}
__device__ __forceinline__ float2 ub2(uint u) {
    union { uint i; float f; } a, b;
    a.i = u << 16; b.i = u & 0xffff0000u;
    return make_float2(a.f, b.f);
}
// unpack to ext-vector float2 (v_pk_add_f32-friendly accumulation)
__device__ __forceinline__ f32x2 up2(uint u) {
    union { uint i; float f; } lo, hi;
    lo.i = u << 16; hi.i = u & 0xffff0000u;
    f32x2 r; r.x = lo.f; r.y = hi.f;
    return r;
}

// ---------------------------------------------------------------------------
// One-pass multisplit (R10-proven): edges cached in registers (bulk prefetch
// = the ILP that matters), LDS histogram, one padded global atomic per
// (bucket, block) reserves the range, scatter from registers.
__global__ __launch_bounds__(256) void scatter_kernel(const int* __restrict__ src,
                                                      const int* __restrict__ dst,
                                                      int* __restrict__ bcnt,
                                                      uint* __restrict__ pairs) {
    __shared__ int h[4 * NB];
    __shared__ int start[NB];
    __shared__ int cur[NB];
    int t = threadIdx.x;
    int base = blockIdx.x * EPB;

    int rs[16], rd[16];
#pragma unroll
    for (int j = 0; j < 16; ++j) {
        int e = base + j * 256 + t;
        if (e < N_EDGES) { rs[j] = src[e]; rd[j] = dst[e]; }
        else rd[j] = -1;
    }
    for (int i = t; i < 4 * NB; i += 256) h[i] = 0;
    __syncthreads();
    int w = t >> 6;
#pragma unroll
    for (int j = 0; j < 16; ++j)
        if (rd[j] >= 0) atomicAdd(&h[w * NB + (rd[j] >> 8)], 1);
    __syncthreads();
    for (int b = t; b < NB; b += 256) {
        int tot = h[b] + h[NB + b] + h[2 * NB + b] + h[3 * NB + b];
        start[b] = tot ? atomicAdd(&bcnt[b * 16], tot) : 0;
        cur[b] = 0;
    }
    __syncthreads();
#pragma unroll
    for (int j = 0; j < 16; ++j) {
        if (rd[j] >= 0) {
            int b = rd[j] >> 8;
            int r = atomicAdd(&cur[b], 1);
            pairs[(size_t)b * CAP + start[b] + r] =
                ((uint)(rd[j] & 255) << 24) | (uint)rs[j];   // src < 2^17
        }
    }
}

// ---------------------------------------------------------------------------
// Per-bucket CSR build (256-node buckets, 512 threads):
// pass 1: 8-way wave-replicated LDS histogram, 4-wide batched loads;
// scan -> rstart/rend/dis; pass 2: 4-wide batched cursor fill of csr_src.
__global__ __launch_bounds__(512) void bucket_csr_kernel(const uint* __restrict__ pairs,
                                                         const int* __restrict__ bcnt,
                                                         int* __restrict__ csr_src,
                                                         int* __restrict__ rstart,
                                                         int* __restrict__ rend,
                                                         float* __restrict__ dis) {
    __shared__ int h8[8 * 256];         // replicated histograms (8 KB)
    __shared__ int h[256];              // combined / scan / cursor
    int b = blockIdx.x;
    int t = threadIdx.x;
    int w = t >> 6;                     // wave 0..7
    int e0 = b * CAP;
    int e1 = e0 + bcnt[b * 16];

    for (int i = t; i < 8 * 256; i += 512) h8[i] = 0;
    __syncthreads();

    int* hw = &h8[w * 256];
    int e = e0 + t;
    for (; e + 1536 < e1; e += 2048) {
        uint p0 = pairs[e], p1 = pairs[e + 512], p2 = pairs[e + 1024], p3 = pairs[e + 1536];
        atomicAdd(&hw[p0 >> 24], 1);
        atomicAdd(&hw[p1 >> 24], 1);
        atomicAdd(&hw[p2 >> 24], 1);
        atomicAdd(&hw[p3 >> 24], 1);
    }
    for (; e < e1; e += 512)
        atomicAdd(&hw[pairs[e] >> 24], 1);
    __syncthreads();

    int v = 0;
    if (t < 256) {
#pragma unroll
        for (int j = 0; j < 8; ++j) v += h8[j * 256 + t];
        h[t] = v;
    }
    __syncthreads();
    // inclusive scan of h[256]
#pragma unroll
    for (int o = 1; o < 256; o <<= 1) {
        int x = (t >= o && t < 256) ? h[t - o] : 0;
        __syncthreads();
        if (t < 256) h[t] += x;
        __syncthreads();
    }
    int excl = (t < 256) ? h[t] - v : 0;
    int n = b * 256 + t;
    if (t < 256 && n < N_NODES) {
        rstart[n] = e0 + excl;
        rend[n] = e0 + excl + v;
        dis[n] = rsqrtf((float)v + 1.0f);
    }
    __syncthreads();
    if (t < 256) h[t] = e0 + excl;      // cursor
    __syncthreads();

    e = e0 + t;
    for (; e + 1536 < e1; e += 2048) {
        uint p0 = pairs[e], p1 = pairs[e + 512], p2 = pairs[e + 1024], p3 = pairs[e + 1536];
        int q0 = atomicAdd(&h[p0 >> 24], 1);
        int q1 = atomicAdd(&h[p1 >> 24], 1);
        int q2 = atomicAdd(&h[p2 >> 24], 1);
        int q3 = atomicAdd(&h[p3 >> 24], 1);
        csr_src[q0] = (int)(p0 & 0xFFFFFFu);
        csr_src[q1] = (int)(p1 & 0xFFFFFFu);
        csr_src[q2] = (int)(p2 & 0xFFFFFFu);
        csr_src[q3] = (int)(p3 & 0xFFFFFFu);
    }
    for (; e < e1; e += 512) {
        uint p = pairs[e];
        int pos = atomicAdd(&h[p >> 24], 1);
        csr_src[pos] = (int)(p & 0xFFFFFFu);
    }
}

// ---------------------------------------------------------------------------
// GEMM1: Y[M,64](bf16) = (X[M,128] @ W[128,64]) * dis[row].  X fp32.
// block: 128 rows x 64 ch; thread: 4 rows x 8 ch. Register-prefetch staging.
__global__ __launch_bounds__(256) void gemm1_kernel(const float* __restrict__ X,
                                                    const float* __restrict__ W,
                                                    const float* __restrict__ dis,
                                                    uint* __restrict__ Y) {
    __shared__ float Wl[IN_CH * 64];
    __shared__ float Xs[128 * 33];
    int t = threadIdx.x;
    for (int idx = t; idx < IN_CH * 64; idx += 256) Wl[idx] = W[idx];

    int r0 = (t >> 3) * 4;
    int c0 = (t & 7) * 8;
    int rowBase = blockIdx.x * 128;

    float acc[4][8];
#pragma unroll
    for (int a = 0; a < 4; ++a)
#pragma unroll
        for (int c = 0; c < 8; ++c) acc[a][c] = 0.f;

    int srow = t >> 1;
    int shh = (t & 1) * 16;
    bool sok = (rowBase + srow) < N_NODES;
    const float* xbase = X + (size_t)(rowBase + srow) * IN_CH + shh;

    float4 nx[4];
#pragma unroll
    for (int f = 0; f < 4; ++f)
        nx[f] = sok ? *reinterpret_cast<const float4*>(xbase + f * 4)
                    : make_float4(0.f, 0.f, 0.f, 0.f);

    for (int kc = 0; kc < IN_CH; kc += 32) {
        if (kc) __syncthreads();
#pragma unroll
        for (int f = 0; f < 4; ++f) {
            int o = srow * 33 + shh + f * 4;
            Xs[o] = nx[f].x; Xs[o + 1] = nx[f].y; Xs[o + 2] = nx[f].z; Xs[o + 3] = nx[f].w;
        }
        __syncthreads();
        if (kc + 32 < IN_CH) {
#pragma unroll
            for (int f = 0; f < 4; ++f)
                nx[f] = sok ? *reinterpret_cast<const float4*>(xbase + kc + 32 + f * 4)
                            : make_float4(0.f, 0.f, 0.f, 0.f);
        }
#pragma unroll
        for (int kk = 0; kk < 32; ++kk) {
            const float4 wa = *reinterpret_cast<const float4*>(&Wl[(kc + kk) * 64 + c0]);
            const float4 wb = *reinterpret_cast<const float4*>(&Wl[(kc + kk) * 64 + c0 + 4]);
            float xr[4];
#pragma unroll
            for (int a = 0; a < 4; ++a) xr[a] = Xs[(r0 + a) * 33 + kk];
#pragma unroll
            for (int a = 0; a < 4; ++a) {
                acc[a][0] += xr[a] * wa.x; acc[a][1] += xr[a] * wa.y;
                acc[a][2] += xr[a] * wa.z; acc[a][3] += xr[a] * wa.w;
                acc[a][4] += xr[a] * wb.x; acc[a][5] += xr[a] * wb.y;
                acc[a][6] += xr[a] * wb.z; acc[a][7] += xr[a] * wb.w;
            }
        }
    }
#pragma unroll
    for (int a = 0; a < 4; ++a) {
        int row = rowBase + r0 + a;
        if (row < N_NODES) {
            float d = dis[row];
            uint4 o;
            o.x = pack2(acc[a][0] * d, acc[a][1] * d);
            o.y = pack2(acc[a][2] * d, acc[a][3] * d);
            o.z = pack2(acc[a][4] * d, acc[a][5] * d);
            o.w = pack2(acc[a][6] * d, acc[a][7] * d);
            *reinterpret_cast<uint4*>(Y + (size_t)row * 32 + (t & 7) * 4) = o;
        }
    }
}

// ---------------------------------------------------------------------------
// GEMM2: Y[M,64](bf16) = (relu(X)[M,64] @ W[64,64]) * dis[row].  X bf16 packed.
__global__ __launch_bounds__(256) void gemm2_kernel(const uint* __restrict__ X,
                                                    const float* __restrict__ W,
                                                    const float* __restrict__ dis,
                                                    uint* __restrict__ Y) {
    __shared__ float Wl[HID * 64];
    __shared__ float Xs[128 * 33];
    int t = threadIdx.x;
    for (int idx = t; idx < HID * 64; idx += 256) Wl[idx] = W[idx];

    int r0 = (t >> 3) * 4;
    int c0 = (t & 7) * 8;
    int rowBase = blockIdx.x * 128;

    float acc[4][8];
#pragma unroll
    for (int a = 0; a < 4; ++a)
#pragma unroll
        for (int c = 0; c < 8; ++c) acc[a][c] = 0.f;

    int srow = t >> 1;
    int shh = (t & 1) * 16;
    bool sok = (rowBase + srow) < N_NODES;
    const uint* xbase = X + (size_t)(rowBase + srow) * 32 + (t & 1) * 8;

    uint4 n0_ = make_uint4(0, 0, 0, 0), n1_ = n0_;
    if (sok) {
        n0_ = *reinterpret_cast<const uint4*>(xbase);
        n1_ = *reinterpret_cast<const uint4*>(xbase + 4);
    }

    for (int kc = 0; kc < HID; kc += 32) {
        if (kc) __syncthreads();
        {
            uint us[8] = {n0_.x, n0_.y, n0_.z, n0_.w, n1_.x, n1_.y, n1_.z, n1_.w};
            int o = srow * 33 + shh;
#pragma unroll
            for (int j = 0; j < 8; ++j) {
                float2 f = ub2(us[j]);
                Xs[o + 2 * j]     = fmaxf(f.x, 0.f);
                Xs[o + 2 * j + 1] = fmaxf(f.y, 0.f);
            }
        }
        __syncthreads();
        if (kc + 32 < HID && sok) {
            n0_ = *reinterpret_cast<const uint4*>(xbase + 16);
            n1_ = *reinterpret_cast<const uint4*>(xbase + 20);
        }
#pragma unroll
        for (int kk = 0; kk < 32; ++kk) {
            const float4 wa = *reinterpret_cast<const float4*>(&Wl[(kc + kk) * 64 + c0]);
            const float4 wb = *reinterpret_cast<const float4*>(&Wl[(kc + kk) * 64 + c0 + 4]);
            float xr[4];
#pragma unroll
            for (int a = 0; a < 4; ++a) xr[a] = Xs[(r0 + a) * 33 + kk];
#pragma unroll
            for (int a = 0; a < 4; ++a) {
                acc[a][0] += xr[a] * wa.x; acc[a][1] += xr[a] * wa.y;
                acc[a][2] += xr[a] * wa.z; acc[a][3] += xr[a] * wa.w;
                acc[a][4] += xr[a] * wb.x; acc[a][5] += xr[a] * wb.y;
                acc[a][6] += xr[a] * wb.z; acc[a][7] += xr[a] * wb.w;
            }
        }
    }
#pragma unroll
    for (int a = 0; a < 4; ++a) {
        int row = rowBase + r0 + a;
        if (row < N_NODES) {
            float d = dis[row];
            uint4 o;
            o.x = pack2(acc[a][0] * d, acc[a][1] * d);
            o.y = pack2(acc[a][2] * d, acc[a][3] * d);
            o.z = pack2(acc[a][4] * d, acc[a][5] * d);
            o.w = pack2(acc[a][6] * d, acc[a][7] * d);
            *reinterpret_cast<uint4*>(Y + (size_t)row * 32 + (t & 7) * 4) = o;
        }
    }
}

// ---------------------------------------------------------------------------
// wave per node, 8 edges concurrent (8 lanes/edge, bf16x8 = 16B per lane),
// 16-edge unroll, f32x2 packed accumulation (v_pk_add_f32):
// B[i] = bf16(bias + dis[i] * (A'[i] + sum A'[src])),  A' = (X@W)*dis  (bf16)
__global__ __launch_bounds__(256) void gather_kernel(const int* __restrict__ rstart,
                                                     const int* __restrict__ rend,
                                                     const int* __restrict__ csr_src,
                                                     const float* __restrict__ dis,
                                                     const float* __restrict__ bias,
                                                     const uint* __restrict__ A,
                                                     uint* __restrict__ B) {
    int i = blockIdx.x * 4 + (threadIdx.x >> 6);
    if (i >= N_NODES) return;
    int lane = threadIdx.x & 63;
    int q = lane >> 3;               // which of 8 concurrent edges
    int cu = (lane & 7) * 4;         // uint4 offset in 32-uint row (8 channels)

    float4 bi0 = *reinterpret_cast<const float4*>(&bias[(lane & 7) * 8]);
    float4 bi1 = *reinterpret_cast<const float4*>(&bias[(lane & 7) * 8 + 4]);

    int e = rstart[i];
    int end = rend[i];

    f32x2 a[4], b[4];
#pragma unroll
    for (int j = 0; j < 4; ++j) { a[j] = (f32x2)0.f; b[j] = (f32x2)0.f; }

    if (q == 0) {                    // self term (already *dis[i])
        uint4 u = *reinterpret_cast<const uint4*>(&A[(size_t)i * 32 + cu]);
        a[0] += up2(u.x); a[1] += up2(u.y); a[2] += up2(u.z); a[3] += up2(u.w);
    }
    for (; e + 16 <= end; e += 16) {
        int s0 = csr_src[e + q];
        int s1 = csr_src[e + 8 + q];
        uint4 u0 = *reinterpret_cast<const uint4*>(&A[(size_t)s0 * 32 + cu]);
        uint4 u1 = *reinterpret_cast<const uint4*>(&A[(size_t)s1 * 32 + cu]);
        a[0] += up2(u0.x); a[1] += up2(u0.y); a[2] += up2(u0.z); a[3] += up2(u0.w);
        b[0] += up2(u1.x); b[1] += up2(u1.y); b[2] += up2(u1.z); b[3] += up2(u1.w);
    }
    for (; e + 8 <= end; e += 8) {
        int s = csr_src[e + q];
        uint4 u = *reinterpret_cast<const uint4*>(&A[(size_t)s * 32 + cu]);
        a[0] += up2(u.x); a[1] += up2(u.y); a[2] += up2(u.z); a[3] += up2(u.w);
    }
    if (e + q < end) {
        int s = csr_src[e + q];
        uint4 u = *reinterpret_cast<const uint4*>(&A[(size_t)s * 32 + cu]);
        b[0] += up2(u.x); b[1] += up2(u.y); b[2] += up2(u.z); b[3] += up2(u.w);
    }
    float r[8];
#pragma unroll
    for (int j = 0; j < 4; ++j) {
        f32x2 s = a[j] + b[j];
        r[2 * j] = s.x; r[2 * j + 1] = s.y;
    }
#pragma unroll
    for (int j = 0; j < 8; ++j) {
        r[j] += __shfl_xor(r[j], 8);
        r[j] += __shfl_xor(r[j], 16);
        r[j] += __shfl_xor(r[j], 32);
    }
    if (q == 0) {
        float d = dis[i];
        uint4 o;
        o.x = pack2(bi0.x + d * r[0], bi0.y + d * r[1]);
        o.y = pack2(bi0.z + d * r[2], bi0.w + d * r[3]);
        o.z = pack2(bi1.x + d * r[4], bi1.y + d * r[5]);
        o.w = pack2(bi1.z + d * r[6], bi1.w + d * r[7]);
        *reinterpret_cast<uint4*>(B + (size_t)i * 32 + (lane & 7) * 4) = o;
    }
}

// ---------------------------------------------------------------------------
// pool over bf16 B: batch is sorted -> run-length accumulate per half-wave
// (16 nodes each; 32 lanes x 2 ch cover the 64-ch row), relu fused.
__global__ __launch_bounds__(256) void pool_kernel(const uint* __restrict__ B,
                                                   const int* __restrict__ batch,
                                                   float* __restrict__ sums,
                                                   float* __restrict__ cnt) {
    int w = blockIdx.x * 4 + (threadIdx.x >> 6);
    int half = (threadIdx.x >> 5) & 1;
    int l = threadIdx.x & 31;           // uint index (channels 2l, 2l+1)
    int n0 = w * 32 + half * 16;
    if (n0 >= N_NODES) return;
    int n1 = min(n0 + 16, N_NODES);
    int curg = batch[n0];
    float a0 = 0.f, a1 = 0.f;
    int run = 0;
    for (int n = n0; n < n1; ++n) {
        int g = batch[n];
        if (g != curg) {
            atomicAdd(&sums[curg * 64 + 2 * l], a0);
            atomicAdd(&sums[curg * 64 + 2 * l + 1], a1);
            if (l == 0) atomicAdd(&cnt[curg], (float)run);
            curg = g; a0 = 0.f; a1 = 0.f; run = 0;
        }
        float2 f = ub2(B[(size_t)n * 32 + l]);
        a0 += fmaxf(f.x, 0.f);
        a1 += fmaxf(f.y, 0.f);
        run++;
    }
    atomicAdd(&sums[curg * 64 + 2 * l], a0);
    atomicAdd(&sums[curg * 64 + 2 * l + 1], a1);
    if (l == 0) atomicAdd(&cnt[curg], (float)run);
}

__global__ __launch_bounds__(256) void final_kernel(const float* __restrict__ sums,
                                                    const float* __restrict__ cnt,
                                                    float* __restrict__ out) {
    int idx = blockIdx.x * 256 + threadIdx.x;
    if (idx < N_GRAPHS * 64) out[idx] = sums[idx] / fmaxf(cnt[idx >> 6], 1.0f);
}

// ---------------------------------------------------------------------------
extern "C" void kernel_launch(void* const* d_in, const int* in_sizes, int n_in,
                              void* d_out, int out_size, void* d_ws, size_t ws_size,
                              hipStream_t stream) {
    const float* x     = (const float*)d_in[0];
    const int*   edge  = (const int*)d_in[1];   // [2, E]: row0 = src, row1 = dst
    const int*   batch = (const int*)d_in[2];
    const float* W1    = (const float*)d_in[3];
    const float* b1    = (const float*)d_in[4];
    const float* W2    = (const float*)d_in[5];
    const float* b2    = (const float*)d_in[6];
    float* out = (float*)d_out;

    // workspace layout (elements)
    uint*  A        = (uint*)d_ws;                        // 3,200,000 u (bf16 A)
    uint*  B        = A + (size_t)N_NODES * 32;           // 3,200,000 u (bf16 B)
    uint*  pairs    = B + (size_t)N_NODES * 32;           // NB*CAP = 4,003,840 u
    int*   csr_src  = (int*)(pairs + (size_t)NB * CAP);   // NB*CAP = 4,003,840 i
    float* dis      = (float*)(csr_src + (size_t)NB * CAP); // 100,000 f
    int*   rstart   = (int*)(dis + N_NODES);              // 100,000 i
    int*   rend     = rstart + N_NODES;                   // 100,000 i
    float* sums     = (float*)(rend + N_NODES);           // 32,768 f
    float* cnt_f    = sums + (size_t)N_GRAPHS * 64;       // 512 f
    int*   bcnt     = (int*)(cnt_f + N_GRAPHS);           // NB*16 = 6,256 i (padded)
    // total ~59 MB

    const int* src = edge;
    const int* dst = edge + N_EDGES;

    // zero sums + cnt + bcnt in one shot (contiguous)
    hipMemsetAsync(sums, 0, (N_GRAPHS * 64 + N_GRAPHS + NB * 16) * sizeof(float), stream);

    // CSR build: one-pass multisplit + per-bucket local fill
    scatter_kernel<<<NBLK, 256, 0, stream>>>(src, dst, bcnt, pairs);
    bucket_csr_kernel<<<NB, 512, 0, stream>>>(pairs, bcnt, csr_src, rstart, rend, dis);

    // layer 1: A = bf16((x@W1)*dis) ; B = bf16(b1 + dis*(A[i] + sum A[src]))
    gemm1_kernel<<<(N_NODES + 127) / 128, 256, 0, stream>>>(x, W1, dis, A);
    gather_kernel<<<(N_NODES + 3) / 4, 256, 0, stream>>>(rstart, rend, csr_src, dis, b1, A, B);

    // layer 2 (relu fused into GEMM2 staging)
    gemm2_kernel<<<(N_NODES + 127) / 128, 256, 0, stream>>>(B, W2, dis, A);
    gather_kernel<<<(N_NODES + 3) / 4, 256, 0, stream>>>(rstart, rend, csr_src, dis, b2, A, B);

    // pool (relu fused) + finalize
    pool_kernel<<<(N_NODES + 127) / 128, 256, 0, stream>>>(B, batch, sums, cnt_f);
    final_kernel<<<(N_GRAPHS * 64 + 255) / 256, 256, 0, stream>>>(sums, cnt_f, out);
}